// Round 17
// baseline (86.730 us; speedup 1.0000x reference)
//
#include <hip/hip_runtime.h>
#include <hip/hip_bf16.h>

// LinearAttention fused pipeline for MI355X (gfx950). 5 kernels:
//   pre_k    : rmsnorm(x)->xn bf16  +  w_qkv transpose->WqkvT (head-interleaved kv)
//   gemm1_k  : xn @ WqkvT; q-tiles -> feature-softmax -> QS;
//              kv-tiles -> exp(k),v -> in-block EK^T·V MFMA -> pctx(bf16)/pden
//              HALF-TILE pipeline: BK=32 quarters, 4 LDS quarter-buffers,
//              counted vmcnt(6), 3 halves in flight, 2 blocks/CU.
//   ctx_final: reduce 32 bf16 chunks + mem_kv softmax denom -> ctx (256 blocks)
//   make_w2t : fold ctx into w_out -> W2T bf16 (256 blocks)
//   gemm2rms : QS @ W2T^T + bias -> rmsnorm -> d_out (f32), LDS-staged
// Workspace layout (bytes):
//   [0        , 16777216)  xn bf16 [16384][512]
//   [16777216 , 18350080)  WqkvT bf16 [1536][512] (rows 512+: h-interleaved k|v)
//   [18350080 , 26738688)  pctx bf16 [1024][64][64]
//   [51904512 , 68681728)  QS bf16 [16384][512]
//   [68681728 , 68943872)  pden f32 [1024][64]
//   [68943872 , 69468160)  ctx  f32 [32][64][64]
//   [69468160 , 71565312)  W2T bf16 [4][512][512]

typedef __attribute__((ext_vector_type(8))) __bf16 bf16x8;
typedef __attribute__((ext_vector_type(4))) __bf16 bf16x4;
typedef __attribute__((ext_vector_type(2))) __bf16 bf16x2;
typedef __attribute__((ext_vector_type(4))) float f32x4;

#define SQRT_DIM 22.627416997969522f

__device__ __forceinline__ void gload_lds16(const void* g, void* l) {
  __builtin_amdgcn_global_load_lds((__attribute__((address_space(1))) void*)g,
                                   (__attribute__((address_space(3))) void*)l, 16, 0, 0);
}

// ---------- K0: fused rmsnorm (blocks 0..4095) + w_qkv transpose (blocks 4096..4287)
__global__ __launch_bounds__(256) void pre_k(const float* __restrict__ x,
                                             const float* __restrict__ nw,
                                             __bf16* __restrict__ xn,
                                             const float* __restrict__ wqkv,
                                             __bf16* __restrict__ WqkvT) {
  __shared__ float tbuf[64][65];
  const int bid = blockIdx.x;
  const int tid = threadIdx.x;
  if (bid < 4096) {
    const int row = bid * 4 + (tid >> 6);
    const int lane = tid & 63;
    const float4* xr = (const float4*)(x + (size_t)row * 512);
    float4 v0 = xr[lane], v1 = xr[lane + 64];
    float s = v0.x * v0.x + v0.y * v0.y + v0.z * v0.z + v0.w * v0.w +
              v1.x * v1.x + v1.y * v1.y + v1.z * v1.z + v1.w * v1.w;
#pragma unroll
    for (int m = 1; m < 64; m <<= 1) s += __shfl_xor(s, m);
    const float sc = SQRT_DIM / fmaxf(sqrtf(s), 1e-12f);
    const float4* wr4 = (const float4*)nw;
    float4 w0 = wr4[lane], w1 = wr4[lane + 64];
    __bf16* o = xn + (size_t)row * 512;
    bf16x4 a, b2;
    a[0] = (__bf16)(v0.x * sc * w0.x); a[1] = (__bf16)(v0.y * sc * w0.y);
    a[2] = (__bf16)(v0.z * sc * w0.z); a[3] = (__bf16)(v0.w * sc * w0.w);
    b2[0] = (__bf16)(v1.x * sc * w1.x); b2[1] = (__bf16)(v1.y * sc * w1.y);
    b2[2] = (__bf16)(v1.z * sc * w1.z); b2[3] = (__bf16)(v1.w * sc * w1.w);
    *(bf16x4*)(o + lane * 4) = a;
    *(bf16x4*)(o + 256 + lane * 4) = b2;
  } else {
    const int t = bid - 4096;  // 0..191 = bx(24) x by(8)
    const int bx = t % 24, by = t / 24;
    const int n0 = bx * 64, k0 = by * 64;
    const int r = tid >> 4, c4 = (tid & 15) * 4;
#pragma unroll
    for (int p = 0; p < 4; ++p) {
      float4 v = *(const float4*)(wqkv + (size_t)(k0 + p * 16 + r) * 1536 + n0 + c4);
      tbuf[p * 16 + r][c4 + 0] = v.x;
      tbuf[p * 16 + r][c4 + 1] = v.y;
      tbuf[p * 16 + r][c4 + 2] = v.z;
      tbuf[p * 16 + r][c4 + 3] = v.w;
    }
    __syncthreads();
    const int base = (n0 < 512) ? n0
                     : (n0 < 1024 ? 512 + ((n0 - 512) >> 6) * 128
                                  : 512 + ((n0 - 1024) >> 6) * 128 + 64);
#pragma unroll
    for (int p = 0; p < 4; ++p) {
      int c = p * 256 + tid;
      int rn = c >> 4, cc = (c & 15) * 4;
      bf16x4 o;
#pragma unroll
      for (int j = 0; j < 4; ++j) o[j] = (__bf16)tbuf[cc + j][rn];
      *(bf16x4*)(WqkvT + (size_t)(base + rn) * 512 + k0 + cc) = o;
    }
  }
}

// ---------- GEMM1: BM=128 BN=128, 512 thr (8 waves 4Mx2N), HALF-TILE pipeline:
// BK=32 halves, 4 quarter-buffers (A 8KB + B 8KB each) in 64 KB -> 2 blocks/CU.
// Per half h (q=h&3): 6 ds_reads from Q[q] -> lgkmcnt(0)+barrier (Q[q] consumed)
// -> stage(q, h+4) (2 loads/thread) -> 8 MFMA (setprio) -> vmcnt(6)+barrier.
// 2D chunk swizzle c^(r&3)^((r>>2)&3): linear gload_lds dest, 2-way-free reads.
__global__ __launch_bounds__(512) void gemm1_k(const __bf16* __restrict__ A,
                                               const __bf16* __restrict__ BT,
                                               __bf16* __restrict__ QS,
                                               __bf16* __restrict__ pctx,
                                               float* __restrict__ pden) {
  __shared__ __align__(16) char smem[65536];
  const int K = 512;
  const int NH = 16;  // K / 32 half-tiles
  const int NX = 12;
  const int tid = threadIdx.x;
  const int lane = tid & 63;
  const int wave = tid >> 6;
  const int wr = (wave >> 1) * 32;  // 4 M-groups of 32 rows
  const int wc = (wave & 1) * 64;   // 2 N-groups of 64 cols
  const int l15 = lane & 15, lg = lane >> 4;  // lg in 0..3 = k-chunk of 8
  const int cpx = gridDim.x >> 3;
  const int fid = blockIdx.x;
  const int tile = (fid & 7) * cpx + (fid >> 3);
  const int my = tile / NX;
  const int m0 = my * 128;
  const int n0 = (tile - my * NX) * 128;

  f32x4 acc[2][4] = {};

  // stage half-tile h into quarter q: A rows -> smem[q*8192 + tid*16],
  // B rows -> smem[32768 + q*8192 + tid*16]; source chunk pre-swizzled.
  auto stage = [&](int q, int h) {
    const int row = tid >> 2, c = tid & 3;
    const int sc = c ^ (row & 3) ^ ((row >> 2) & 3);
    gload_lds16((const char*)(A + (size_t)(m0 + row) * K + h * 32) + sc * 16,
                smem + q * 8192 + tid * 16);
    gload_lds16((const char*)(BT + (size_t)(n0 + row) * K + h * 32) + sc * 16,
                smem + 32768 + q * 8192 + tid * 16);
  };

  stage(0, 0);
  stage(1, 1);
  stage(2, 2);
  stage(3, 3);
  asm volatile("s_waitcnt vmcnt(6)" ::: "memory");  // Q[0] done; 1..3 in flight
  __builtin_amdgcn_s_barrier();

  for (int h = 0; h < NH; ++h) {
    const int q = h & 3;
    const __bf16* Aq = (const __bf16*)(smem + q * 8192);
    const __bf16* Bq = (const __bf16*)(smem + 32768 + q * 8192);
    bf16x8 af[2], bfr[4];
#pragma unroll
    for (int i = 0; i < 2; ++i) {
      int r = wr + i * 16 + l15;
      af[i] = *(const bf16x8*)(&Aq[r * 32 + (lg ^ (r & 3) ^ ((r >> 2) & 3)) * 8]);
    }
#pragma unroll
    for (int i = 0; i < 4; ++i) {
      int r = wc + i * 16 + l15;
      bfr[i] = *(const bf16x8*)(&Bq[r * 32 + (lg ^ (r & 3) ^ ((r >> 2) & 3)) * 8]);
    }
    asm volatile("s_waitcnt lgkmcnt(0)" ::: "memory");
    __builtin_amdgcn_sched_barrier(0);
    __builtin_amdgcn_s_barrier();  // Q[q] consumed by all waves
    if (h + 4 < NH) stage(q, h + 4);
    __builtin_amdgcn_s_setprio(1);
#pragma unroll
    for (int mi = 0; mi < 2; ++mi)
#pragma unroll
      for (int ni = 0; ni < 4; ++ni)
        acc[mi][ni] = __builtin_amdgcn_mfma_f32_16x16x32_bf16(af[mi], bfr[ni],
                                                              acc[mi][ni], 0, 0, 0);
    __builtin_amdgcn_s_setprio(0);
    if (h < NH - 1) {
      asm volatile("s_waitcnt vmcnt(6)" ::: "memory");  // Q[(h+1)&3] ready (FIFO)
      __builtin_amdgcn_s_barrier();
    }
  }

  if (n0 < 512) {
    // ---- q epilogue: feature-softmax -> LDS repack -> coalesced store
    __bf16* Cs = (__bf16*)smem;  // [128][132]
#pragma unroll
    for (int mi = 0; mi < 2; ++mi)
#pragma unroll
      for (int r = 0; r < 4; ++r) {
        float v0_ = acc[mi][0][r], v1_ = acc[mi][1][r], v2_ = acc[mi][2][r],
              v3_ = acc[mi][3][r];
        float mx = fmaxf(fmaxf(v0_, v1_), fmaxf(v2_, v3_));
#pragma unroll
        for (int m = 1; m < 16; m <<= 1) mx = fmaxf(mx, __shfl_xor(mx, m));
        float e0 = __expf(v0_ - mx), e1 = __expf(v1_ - mx),
              e2 = __expf(v2_ - mx), e3 = __expf(v3_ - mx);
        float s = e0 + e1 + e2 + e3;
#pragma unroll
        for (int m = 1; m < 16; m <<= 1) s += __shfl_xor(s, m);
        float inv = 0.125f / s;  // * C^-0.5
        int row = wr + mi * 16 + lg * 4 + r;
        Cs[row * 132 + wc + l15] = (__bf16)(e0 * inv);
        Cs[row * 132 + wc + 16 + l15] = (__bf16)(e1 * inv);
        Cs[row * 132 + wc + 32 + l15] = (__bf16)(e2 * inv);
        Cs[row * 132 + wc + 48 + l15] = (__bf16)(e3 * inv);
      }
    __syncthreads();
    const int sr = tid >> 4, sc2 = tid & 15;
#pragma unroll
    for (int p = 0; p < 4; ++p) {
      int row = p * 32 + sr;
      bf16x8 v = *(const bf16x8*)(&Cs[row * 132 + sc2 * 8]);
      *(bf16x8*)(QS + (size_t)(m0 + row) * 512 + n0 + sc2 * 8) = v;
    }
  } else {
    // ---- kv epilogue: swizzled transposed exp(k)/v tiles, EK^T·V MFMA, pctx/pden
    const int h = (n0 >> 7) - 4;
    __bf16* EKs = (__bf16*)smem;           // [64][128], chunk^(row&7) swizzle
    __bf16* Vs = (__bf16*)(smem + 16384);  // [64][128]
    float* denp = (float*)(smem + 32768);  // [4][64]
    float p[4] = {0.0f, 0.0f, 0.0f, 0.0f};
#pragma unroll
    for (int mi = 0; mi < 2; ++mi) {
      const int tok0 = wr + mi * 16 + lg * 4;
#pragma unroll
      for (int ni = 0; ni < 4; ++ni) {
        const int c = ni * 16 + l15;
        bf16x4 pk;
        if (wc == 0) {
#pragma unroll
          for (int r = 0; r < 4; ++r) {
            float e = __expf(acc[mi][ni][r]);
            p[ni] += e;
            pk[r] = (__bf16)e;
          }
          *(bf16x4*)(&EKs[c * 128 + (((tok0 >> 3) ^ (c & 7)) * 8) + (tok0 & 7)]) = pk;
        } else {
#pragma unroll
          for (int r = 0; r < 4; ++r) pk[r] = (__bf16)acc[mi][ni][r];
          *(bf16x4*)(&Vs[c * 128 + (((tok0 >> 3) ^ (c & 7)) * 8) + (tok0 & 7)]) = pk;
        }
      }
    }
    if (wc == 0) {
#pragma unroll
      for (int ni = 0; ni < 4; ++ni) {
        p[ni] += __shfl_xor(p[ni], 16);
        p[ni] += __shfl_xor(p[ni], 32);
      }
      if (lg == 0) {
#pragma unroll
        for (int ni = 0; ni < 4; ++ni)
          denp[(wave >> 1) * 64 + ni * 16 + l15] = p[ni];
      }
    }
    __syncthreads();
    const int b = m0 >> 12, chunk = (m0 & 4095) >> 7;
    const int wg = (b * 8 + h) * 32 + chunk;
    if (tid < 64)
      pden[(size_t)wg * 64 + tid] =
          denp[tid] + denp[64 + tid] + denp[128 + tid] + denp[192 + tid];
    const int dt = wave >> 1;
    const int eb = (wave & 1) * 2;
    f32x4 cacc[2] = {};
#pragma unroll
    for (int kt2 = 0; kt2 < 4; ++kt2) {
      const int d = dt * 16 + l15;
      bf16x8 af2 = *(const bf16x8*)(&EKs[d * 128 + ((kt2 * 4 + lg) ^ (d & 7)) * 8]);
      bf16x8 bfr2[2];
#pragma unroll
      for (int j = 0; j < 2; ++j) {
        int e = (eb + j) * 16 + l15;
        bfr2[j] = *(const bf16x8*)(&Vs[e * 128 + ((kt2 * 4 + lg) ^ (e & 7)) * 8]);
      }
#pragma unroll
      for (int j = 0; j < 2; ++j)
        cacc[j] = __builtin_amdgcn_mfma_f32_16x16x32_bf16(af2, bfr2[j], cacc[j], 0, 0, 0);
    }
    __bf16* op = pctx + (size_t)wg * 4096;
#pragma unroll
    for (int j = 0; j < 2; ++j) {
      int e = (eb + j) * 16 + l15;
#pragma unroll
      for (int r = 0; r < 4; ++r) {
        int d = dt * 16 + lg * 4 + r;
        op[d * 64 + e] = (__bf16)cacc[j][r];
      }
    }
  }
}

// ---------- GEMM2 fused with bias + out-RMSNorm. BM=64 x BN=512 x BK=64.
// LDS-staged, counted-vmcnt 2-deep schedule (proven R13 version).
__global__ __launch_bounds__(512) void gemm2rms(const __bf16* __restrict__ QS,
                                                const __bf16* __restrict__ W2T,
                                                const float* __restrict__ bias,
                                                const float* __restrict__ onw,
                                                float* __restrict__ out) {
  __shared__ __bf16 As[2][64 * 64];
  __shared__ __bf16 Bs[2][512 * 64];
  __shared__ float rss[64][8];
  const int K = 512;
  const int NT = 8;
  const int tid = threadIdx.x;
  const int lane = tid & 63;
  const int wave = tid >> 6;
  const int wc = wave * 64;
  const int l15 = lane & 15, lg = lane >> 4;
  const int cpx = gridDim.x >> 3;
  const int fid = blockIdx.x;
  const int tile = (fid & 7) * cpx + (fid >> 3);
  const int m0 = tile * 64;
  const __bf16* bt = W2T + (size_t)(m0 >> 12) * 262144;

  f32x4 acc[4][4] = {};

  auto stage = [&](int buf, int k0) {
    {
      int flat = tid;
      int row = flat >> 3;
      int cb = ((flat & 7) ^ (row & 7)) * 16;
      gload_lds16((const char*)(QS + (size_t)(m0 + row) * K + k0) + cb,
                  (char*)(&As[buf][0]) + flat * 16);
    }
#pragma unroll
    for (int it = 0; it < 8; ++it) {
      int flat = it * 512 + tid;
      int row = flat >> 3;
      int cb = ((flat & 7) ^ (row & 7)) * 16;
      gload_lds16((const char*)(bt + (size_t)row * K + k0) + cb,
                  (char*)(&Bs[buf][0]) + flat * 16);
    }
  };

  stage(0, 0);
  stage(1, 64);
  asm volatile("s_waitcnt vmcnt(9)" ::: "memory");
  __builtin_amdgcn_s_barrier();

  for (int kt = 0; kt < NT; ++kt) {
    const int cur = kt & 1;
    bf16x8 a0[4], b0[4], a1[4], b1[4];
    const int sw0 = lg ^ (l15 & 7);
    const int sw1 = (4 + lg) ^ (l15 & 7);
#pragma unroll
    for (int i = 0; i < 4; ++i) {
      a0[i] = *(const bf16x8*)(&As[cur][(i * 16 + l15) * 64 + sw0 * 8]);
      b0[i] = *(const bf16x8*)(&Bs[cur][(wc + i * 16 + l15) * 64 + sw0 * 8]);
      a1[i] = *(const bf16x8*)(&As[cur][(i * 16 + l15) * 64 + sw1 * 8]);
      b1[i] = *(const bf16x8*)(&Bs[cur][(wc + i * 16 + l15) * 64 + sw1 * 8]);
    }
    asm volatile("s_waitcnt lgkmcnt(0)" ::: "memory");
    __builtin_amdgcn_sched_barrier(0);
    __builtin_amdgcn_s_barrier();  // buf[cur] consumed
    if (kt + 2 < NT) stage(cur, (kt + 2) * 64);
    __builtin_amdgcn_s_setprio(1);
#pragma unroll
    for (int mi = 0; mi < 4; ++mi)
#pragma unroll
      for (int ni = 0; ni < 4; ++ni)
        acc[mi][ni] = __builtin_amdgcn_mfma_f32_16x16x32_bf16(a0[mi], b0[ni],
                                                              acc[mi][ni], 0, 0, 0);
    __builtin_amdgcn_s_setprio(0);
    __builtin_amdgcn_s_setprio(1);
#pragma unroll
    for (int mi = 0; mi < 4; ++mi)
#pragma unroll
      for (int ni = 0; ni < 4; ++ni)
        acc[mi][ni] = __builtin_amdgcn_mfma_f32_16x16x32_bf16(a1[mi], b1[ni],
                                                              acc[mi][ni], 0, 0, 0);
    __builtin_amdgcn_s_setprio(0);
    if (kt < NT - 1) {
      if (kt + 2 < NT)
        asm volatile("s_waitcnt vmcnt(9)" ::: "memory");
      else
        asm volatile("s_waitcnt vmcnt(0)" ::: "memory");
      __builtin_amdgcn_s_barrier();
    }
  }

  float bv[4], wv[4];
#pragma unroll
  for (int ni = 0; ni < 4; ++ni) {
    int col = wc + ni * 16 + l15;
    bv[ni] = bias[col];
    wv[ni] = onw[col];
  }
  float vv[4][4][4];
#pragma unroll
  for (int mi = 0; mi < 4; ++mi)
#pragma unroll
    for (int ni = 0; ni < 4; ++ni)
#pragma unroll
      for (int r = 0; r < 4; ++r) vv[mi][ni][r] = acc[mi][ni][r] + bv[ni];
#pragma unroll
  for (int mi = 0; mi < 4; ++mi)
#pragma unroll
    for (int r = 0; r < 4; ++r) {
      float ps = vv[mi][0][r] * vv[mi][0][r] + vv[mi][1][r] * vv[mi][1][r] +
                 vv[mi][2][r] * vv[mi][2][r] + vv[mi][3][r] * vv[mi][3][r];
#pragma unroll
      for (int m = 1; m < 16; m <<= 1) ps += __shfl_xor(ps, m);
      if (l15 == 0) rss[mi * 16 + lg * 4 + r][wave] = ps;
    }
  __syncthreads();
#pragma unroll
  for (int mi = 0; mi < 4; ++mi)
#pragma unroll
    for (int r = 0; r < 4; ++r) {
      int row = mi * 16 + lg * 4 + r;
      float ss = rss[row][0] + rss[row][1] + rss[row][2] + rss[row][3] +
                 rss[row][4] + rss[row][5] + rss[row][6] + rss[row][7];
      float sc = SQRT_DIM / fmaxf(sqrtf(ss), 1e-12f);
      size_t rb = (size_t)(m0 + row) * 512;
#pragma unroll
      for (int ni = 0; ni < 4; ++ni)
        out[rb + wc + ni * 16 + l15] = vv[mi][ni][r] * sc * wv[ni];
    }
}

// ---------- ctx_final: 256 blocks = bh(32) x dgroup(8). Each block: 8 d-rows.
__global__ __launch_bounds__(256) void ctx_final(const __bf16* __restrict__ pctx,
                                                 const float* __restrict__ pden,
                                                 const float* __restrict__ memkv,
                                                 float* __restrict__ ctx) {
  const int bh = blockIdx.x >> 3, dg = blockIdx.x & 7;
  const int h = bh & 7;
  const int tid = threadIdx.x;
  __shared__ float sden[8][9];
  if (tid < 64) {
    const int dl = tid >> 3, part = tid & 7;
    const int d = dg * 8 + dl;
    float s = 0.0f;
#pragma unroll
    for (int c = 0; c < 4; ++c)
      s += pden[((size_t)bh * 32 + part * 4 + c) * 64 + d];
    if (part == 0) {
#pragma unroll
      for (int m = 0; m < 8; ++m)
        s += __expf(memkv[(size_t)h * 512 + d * 8 + m]);
    }
    sden[dl][part] = s;
  }
  __syncthreads();
  const int dl = tid >> 5, e2 = (tid & 31) * 2;
  const int d = dg * 8 + dl;
  float den = sden[dl][0] + sden[dl][1] + sden[dl][2] + sden[dl][3] +
              sden[dl][4] + sden[dl][5] + sden[dl][6] + sden[dl][7];
  float invd = 1.0f / den;
  float s0 = 0.0f, s1 = 0.0f;
#pragma unroll
  for (int m = 0; m < 8; ++m) {
    float ek = __expf(memkv[(size_t)h * 512 + d * 8 + m]);
    s0 += ek * memkv[4096 + (size_t)h * 512 + e2 * 8 + m];
    s1 += ek * memkv[4096 + (size_t)h * 512 + (e2 + 1) * 8 + m];
  }
#pragma unroll
  for (int c = 0; c < 32; ++c) {
    bf16x2 p = *(const bf16x2*)(pctx + ((size_t)bh * 32 + c) * 4096 + d * 64 + e2);
    s0 += (float)p[0];
    s1 += (float)p[1];
  }
  float2 o = make_float2(s0 * invd, s1 * invd);
  *(float2*)(ctx + (size_t)bh * 4096 + d * 64 + e2) = o;
}

// ---------- make_w2t: 256 blocks = b(4) x h(8) x jc(8), j0 = jc*64.
__global__ __launch_bounds__(256) void make_w2t(const float* __restrict__ ctx,
                                                const float* __restrict__ wout,
                                                __bf16* __restrict__ W2T) {
  const int wg = blockIdx.x;
  const int b = wg >> 6, h = (wg >> 3) & 7, jc = wg & 7;
  const int j0 = jc * 64;
  const int tid = threadIdx.x;
  __shared__ float cs[64][65];
  __shared__ float wo[64][64];
  const float* ch = ctx + ((size_t)b * 8 + h) * 4096;
#pragma unroll
  for (int it = 0; it < 16; ++it) {
    int flat = it * 256 + tid;
    cs[flat >> 6][flat & 63] = ch[flat];
  }
#pragma unroll
  for (int it = 0; it < 16; ++it) {
    int flat = it * 256 + tid;
    int e = flat >> 6, j = flat & 63;
    wo[e][j] = wout[(size_t)(h * 64 + e) * 512 + j0 + j];
  }
  __syncthreads();
  const int d = tid & 63;
  const int jg = (tid >> 6) * 16;
  for (int jj = 0; jj < 16; ++jj) {
    int j = jg + jj;
    float s = 0.0f;
#pragma unroll
    for (int e = 0; e < 64; ++e) s += cs[d][e] * wo[e][j];
    W2T[(size_t)b * 262144 + (size_t)(j0 + j) * 512 + h * 64 + d] = (__bf16)s;
  }
}

extern "C" void kernel_launch(void* const* d_in, const int* in_sizes, int n_in,
                              void* d_out, int out_size, void* d_ws, size_t ws_size,
                              hipStream_t stream) {
  const float* x = (const float*)d_in[0];
  const float* norm_w = (const float*)d_in[1];
  const float* w_qkv = (const float*)d_in[2];
  const float* mem_kv = (const float*)d_in[3];
  const float* w_out = (const float*)d_in[4];
  const float* b_out = (const float*)d_in[5];
  const float* onw = (const float*)d_in[6];

  char* ws = (char*)d_ws;
  __bf16* xn = (__bf16*)(ws + 0);            // 16 MB
  __bf16* WqkvT = (__bf16*)(ws + 16777216);  // 1.5 MB
  __bf16* pctx = (__bf16*)(ws + 18350080);   // 8 MB (bf16)
  __bf16* QS = (__bf16*)(ws + 51904512);     // 16 MB
  float* pden = (float*)(ws + 68681728);     // 256 KB
  float* ctx = (float*)(ws + 68943872);      // 512 KB
  __bf16* W2T = (__bf16*)(ws + 69468160);    // 2 MB

  pre_k<<<4288, 256, 0, stream>>>(x, norm_w, xn, w_qkv, WqkvT);
  gemm1_k<<<1536, 512, 0, stream>>>(xn, WqkvT, QS, pctx, pden);
  ctx_final<<<256, 256, 0, stream>>>(pctx, pden, mem_kv, ctx);
  make_w2t<<<256, 256, 0, stream>>>(ctx, w_out, W2T);
  gemm2rms<<<256, 512, 0, stream>>>(QS, W2T, b_out, onw, (float*)d_out);
}

// Round 18
// 85.785 us; speedup vs baseline: 1.0110x; 1.0110x over previous
//
#include <hip/hip_runtime.h>
#include <hip/hip_bf16.h>

// LinearAttention fused pipeline for MI355X (gfx950). 5 kernels:
//   pre_k    : rmsnorm(x)->xn bf16  +  w_qkv transpose->WqkvT (head-interleaved kv)
//   gemm1_k  : xn @ WqkvT; q-tiles -> feature-softmax -> QS;
//              kv-tiles -> exp(k),v -> in-block EK^T·V MFMA -> pctx(bf16)/pden
//              BK=64, 2-deep counted-vmcnt (PROVEN 42us config; BK=32 half-tile
//              variant regressed via 5.4M bank conflicts — reverted).
//   ctx_final: reduce 32 bf16 chunks + mem_kv softmax denom -> ctx (256 blocks)
//   make_w2t : fold ctx into w_out -> W2T bf16 (256 blocks)
//   gemm2rms : QS @ W2T^T + bias -> rmsnorm -> d_out (f32), LDS-staged
// Workspace layout (bytes):
//   [0        , 16777216)  xn bf16 [16384][512]
//   [16777216 , 18350080)  WqkvT bf16 [1536][512] (rows 512+: h-interleaved k|v)
//   [18350080 , 26738688)  pctx bf16 [1024][64][64]
//   [51904512 , 68681728)  QS bf16 [16384][512]
//   [68681728 , 68943872)  pden f32 [1024][64]
//   [68943872 , 69468160)  ctx  f32 [32][64][64]
//   [69468160 , 71565312)  W2T bf16 [4][512][512]

typedef __attribute__((ext_vector_type(8))) __bf16 bf16x8;
typedef __attribute__((ext_vector_type(4))) __bf16 bf16x4;
typedef __attribute__((ext_vector_type(2))) __bf16 bf16x2;
typedef __attribute__((ext_vector_type(4))) float f32x4;

#define SQRT_DIM 22.627416997969522f

__device__ __forceinline__ void gload_lds16(const void* g, void* l) {
  __builtin_amdgcn_global_load_lds((__attribute__((address_space(1))) void*)g,
                                   (__attribute__((address_space(3))) void*)l, 16, 0, 0);
}

// ---------- K0: fused rmsnorm (blocks 0..4095) + w_qkv transpose (blocks 4096..4287)
__global__ __launch_bounds__(256) void pre_k(const float* __restrict__ x,
                                             const float* __restrict__ nw,
                                             __bf16* __restrict__ xn,
                                             const float* __restrict__ wqkv,
                                             __bf16* __restrict__ WqkvT) {
  __shared__ float tbuf[64][65];
  const int bid = blockIdx.x;
  const int tid = threadIdx.x;
  if (bid < 4096) {
    const int row = bid * 4 + (tid >> 6);
    const int lane = tid & 63;
    const float4* xr = (const float4*)(x + (size_t)row * 512);
    float4 v0 = xr[lane], v1 = xr[lane + 64];
    float s = v0.x * v0.x + v0.y * v0.y + v0.z * v0.z + v0.w * v0.w +
              v1.x * v1.x + v1.y * v1.y + v1.z * v1.z + v1.w * v1.w;
#pragma unroll
    for (int m = 1; m < 64; m <<= 1) s += __shfl_xor(s, m);
    const float sc = SQRT_DIM / fmaxf(sqrtf(s), 1e-12f);
    const float4* wr4 = (const float4*)nw;
    float4 w0 = wr4[lane], w1 = wr4[lane + 64];
    __bf16* o = xn + (size_t)row * 512;
    bf16x4 a, b2;
    a[0] = (__bf16)(v0.x * sc * w0.x); a[1] = (__bf16)(v0.y * sc * w0.y);
    a[2] = (__bf16)(v0.z * sc * w0.z); a[3] = (__bf16)(v0.w * sc * w0.w);
    b2[0] = (__bf16)(v1.x * sc * w1.x); b2[1] = (__bf16)(v1.y * sc * w1.y);
    b2[2] = (__bf16)(v1.z * sc * w1.z); b2[3] = (__bf16)(v1.w * sc * w1.w);
    *(bf16x4*)(o + lane * 4) = a;
    *(bf16x4*)(o + 256 + lane * 4) = b2;
  } else {
    const int t = bid - 4096;  // 0..191 = bx(24) x by(8)
    const int bx = t % 24, by = t / 24;
    const int n0 = bx * 64, k0 = by * 64;
    const int r = tid >> 4, c4 = (tid & 15) * 4;
#pragma unroll
    for (int p = 0; p < 4; ++p) {
      float4 v = *(const float4*)(wqkv + (size_t)(k0 + p * 16 + r) * 1536 + n0 + c4);
      tbuf[p * 16 + r][c4 + 0] = v.x;
      tbuf[p * 16 + r][c4 + 1] = v.y;
      tbuf[p * 16 + r][c4 + 2] = v.z;
      tbuf[p * 16 + r][c4 + 3] = v.w;
    }
    __syncthreads();
    const int base = (n0 < 512) ? n0
                     : (n0 < 1024 ? 512 + ((n0 - 512) >> 6) * 128
                                  : 512 + ((n0 - 1024) >> 6) * 128 + 64);
#pragma unroll
    for (int p = 0; p < 4; ++p) {
      int c = p * 256 + tid;
      int rn = c >> 4, cc = (c & 15) * 4;
      bf16x4 o;
#pragma unroll
      for (int j = 0; j < 4; ++j) o[j] = (__bf16)tbuf[cc + j][rn];
      *(bf16x4*)(WqkvT + (size_t)(base + rn) * 512 + k0 + cc) = o;
    }
  }
}

// ---------- GEMM1: BM=128 BN=128 BK=64, 512 thr (8 waves 4Mx2N), 2-deep
// counted-vmcnt, T2 swizzle, 64 KB LDS -> 2 blocks/CU = 16 waves/CU.
__global__ __launch_bounds__(512) void gemm1_k(const __bf16* __restrict__ A,
                                               const __bf16* __restrict__ BT,
                                               __bf16* __restrict__ QS,
                                               __bf16* __restrict__ pctx,
                                               float* __restrict__ pden) {
  __shared__ __align__(16) char smem[65536];
  const int K = 512;
  const int NT = 8;
  const int NX = 12;
  const int tid = threadIdx.x;
  const int lane = tid & 63;
  const int wave = tid >> 6;
  const int wr = (wave >> 1) * 32;  // 4 M-groups of 32 rows
  const int wc = (wave & 1) * 64;   // 2 N-groups of 64 cols
  const int l15 = lane & 15, lg = lane >> 4;
  const int cpx = gridDim.x >> 3;
  const int fid = blockIdx.x;
  const int tile = (fid & 7) * cpx + (fid >> 3);
  const int my = tile / NX;
  const int m0 = my * 128;
  const int n0 = (tile - my * NX) * 128;
  const int sw0 = lg ^ (l15 & 7);
  const int sw1 = (4 + lg) ^ (l15 & 7);

  f32x4 acc[2][4] = {};

  auto stage = [&](int buf, int k0) {
#pragma unroll
    for (int it = 0; it < 2; ++it) {
      int flat = it * 512 + tid;
      int row = flat >> 3;
      int cb = ((flat & 7) ^ (row & 7)) * 16;
      gload_lds16((const char*)(A + (size_t)(m0 + row) * K + k0) + cb,
                  smem + buf * 16384 + flat * 16);
    }
#pragma unroll
    for (int it = 0; it < 2; ++it) {
      int flat = it * 512 + tid;
      int row = flat >> 3;
      int cb = ((flat & 7) ^ (row & 7)) * 16;
      gload_lds16((const char*)(BT + (size_t)(n0 + row) * K + k0) + cb,
                  smem + 32768 + buf * 16384 + flat * 16);
    }
  };

  stage(0, 0);
  stage(1, 64);
  asm volatile("s_waitcnt vmcnt(4)" ::: "memory");
  __builtin_amdgcn_s_barrier();

  for (int kt = 0; kt < NT; ++kt) {
    const int cur = kt & 1;
    const __bf16* Asb = (const __bf16*)(smem + cur * 16384);
    const __bf16* Bsb = (const __bf16*)(smem + 32768 + cur * 16384);
    bf16x8 a0[2], b0[4], a1[2], b1[4];
#pragma unroll
    for (int i = 0; i < 2; ++i) {
      a0[i] = *(const bf16x8*)(&Asb[(wr + i * 16 + l15) * 64 + sw0 * 8]);
      a1[i] = *(const bf16x8*)(&Asb[(wr + i * 16 + l15) * 64 + sw1 * 8]);
    }
#pragma unroll
    for (int i = 0; i < 4; ++i) {
      b0[i] = *(const bf16x8*)(&Bsb[(wc + i * 16 + l15) * 64 + sw0 * 8]);
      b1[i] = *(const bf16x8*)(&Bsb[(wc + i * 16 + l15) * 64 + sw1 * 8]);
    }
    asm volatile("s_waitcnt lgkmcnt(0)" ::: "memory");
    __builtin_amdgcn_sched_barrier(0);
    __builtin_amdgcn_s_barrier();  // buf[cur] consumed by all waves
    if (kt + 2 < NT) stage(cur, (kt + 2) * 64);
    __builtin_amdgcn_s_setprio(1);
#pragma unroll
    for (int mi = 0; mi < 2; ++mi)
#pragma unroll
      for (int ni = 0; ni < 4; ++ni)
        acc[mi][ni] = __builtin_amdgcn_mfma_f32_16x16x32_bf16(a0[mi], b0[ni],
                                                              acc[mi][ni], 0, 0, 0);
    __builtin_amdgcn_s_setprio(0);
    __builtin_amdgcn_s_setprio(1);
#pragma unroll
    for (int mi = 0; mi < 2; ++mi)
#pragma unroll
      for (int ni = 0; ni < 4; ++ni)
        acc[mi][ni] = __builtin_amdgcn_mfma_f32_16x16x32_bf16(a1[mi], b1[ni],
                                                              acc[mi][ni], 0, 0, 0);
    __builtin_amdgcn_s_setprio(0);
    if (kt < NT - 1) {
      if (kt + 2 < NT)
        asm volatile("s_waitcnt vmcnt(4)" ::: "memory");
      else
        asm volatile("s_waitcnt vmcnt(0)" ::: "memory");
      __builtin_amdgcn_s_barrier();
    }
  }

  if (n0 < 512) {
    // ---- q epilogue: feature-softmax -> LDS repack -> coalesced store
    __bf16* Cs = (__bf16*)smem;  // [128][132]
#pragma unroll
    for (int mi = 0; mi < 2; ++mi)
#pragma unroll
      for (int r = 0; r < 4; ++r) {
        float v0_ = acc[mi][0][r], v1_ = acc[mi][1][r], v2_ = acc[mi][2][r],
              v3_ = acc[mi][3][r];
        float mx = fmaxf(fmaxf(v0_, v1_), fmaxf(v2_, v3_));
#pragma unroll
        for (int m = 1; m < 16; m <<= 1) mx = fmaxf(mx, __shfl_xor(mx, m));
        float e0 = __expf(v0_ - mx), e1 = __expf(v1_ - mx),
              e2 = __expf(v2_ - mx), e3 = __expf(v3_ - mx);
        float s = e0 + e1 + e2 + e3;
#pragma unroll
        for (int m = 1; m < 16; m <<= 1) s += __shfl_xor(s, m);
        float inv = 0.125f / s;  // * C^-0.5
        int row = wr + mi * 16 + lg * 4 + r;
        Cs[row * 132 + wc + l15] = (__bf16)(e0 * inv);
        Cs[row * 132 + wc + 16 + l15] = (__bf16)(e1 * inv);
        Cs[row * 132 + wc + 32 + l15] = (__bf16)(e2 * inv);
        Cs[row * 132 + wc + 48 + l15] = (__bf16)(e3 * inv);
      }
    __syncthreads();
    const int sr = tid >> 4, sc = tid & 15;
#pragma unroll
    for (int p = 0; p < 4; ++p) {
      int row = p * 32 + sr;
      bf16x8 v = *(const bf16x8*)(&Cs[row * 132 + sc * 8]);
      *(bf16x8*)(QS + (size_t)(m0 + row) * 512 + n0 + sc * 8) = v;
    }
  } else {
    // ---- kv epilogue: swizzled transposed exp(k)/v tiles, EK^T·V MFMA, pctx/pden
    const int h = (n0 >> 7) - 4;
    __bf16* EKs = (__bf16*)smem;           // [64][128], chunk^(row&7) swizzle
    __bf16* Vs = (__bf16*)(smem + 16384);  // [64][128]
    float* denp = (float*)(smem + 32768);  // [4][64]
    float p[4] = {0.0f, 0.0f, 0.0f, 0.0f};
#pragma unroll
    for (int mi = 0; mi < 2; ++mi) {
      const int tok0 = wr + mi * 16 + lg * 4;
#pragma unroll
      for (int ni = 0; ni < 4; ++ni) {
        const int c = ni * 16 + l15;
        bf16x4 pk;
        if (wc == 0) {
#pragma unroll
          for (int r = 0; r < 4; ++r) {
            float e = __expf(acc[mi][ni][r]);
            p[ni] += e;
            pk[r] = (__bf16)e;
          }
          *(bf16x4*)(&EKs[c * 128 + (((tok0 >> 3) ^ (c & 7)) * 8) + (tok0 & 7)]) = pk;
        } else {
#pragma unroll
          for (int r = 0; r < 4; ++r) pk[r] = (__bf16)acc[mi][ni][r];
          *(bf16x4*)(&Vs[c * 128 + (((tok0 >> 3) ^ (c & 7)) * 8) + (tok0 & 7)]) = pk;
        }
      }
    }
    if (wc == 0) {
#pragma unroll
      for (int ni = 0; ni < 4; ++ni) {
        p[ni] += __shfl_xor(p[ni], 16);
        p[ni] += __shfl_xor(p[ni], 32);
      }
      if (lg == 0) {
#pragma unroll
        for (int ni = 0; ni < 4; ++ni)
          denp[(wave >> 1) * 64 + ni * 16 + l15] = p[ni];
      }
    }
    __syncthreads();
    const int b = m0 >> 12, chunk = (m0 & 4095) >> 7;
    const int wg = (b * 8 + h) * 32 + chunk;
    if (tid < 64)
      pden[(size_t)wg * 64 + tid] =
          denp[tid] + denp[64 + tid] + denp[128 + tid] + denp[192 + tid];
    // ctx MFMA: 16 subtiles (4d x 4e), 8 waves x 2: dt = wave>>1, e-base = (wave&1)*2
    const int dt = wave >> 1;
    const int eb = (wave & 1) * 2;
    f32x4 cacc[2] = {};
#pragma unroll
    for (int kt2 = 0; kt2 < 4; ++kt2) {
      const int d = dt * 16 + l15;
      bf16x8 af = *(const bf16x8*)(&EKs[d * 128 + ((kt2 * 4 + lg) ^ (d & 7)) * 8]);
      bf16x8 bfr[2];
#pragma unroll
      for (int j = 0; j < 2; ++j) {
        int e = (eb + j) * 16 + l15;
        bfr[j] = *(const bf16x8*)(&Vs[e * 128 + ((kt2 * 4 + lg) ^ (e & 7)) * 8]);
      }
#pragma unroll
      for (int j = 0; j < 2; ++j)
        cacc[j] = __builtin_amdgcn_mfma_f32_16x16x32_bf16(af, bfr[j], cacc[j], 0, 0, 0);
    }
    __bf16* op = pctx + (size_t)wg * 4096;
#pragma unroll
    for (int j = 0; j < 2; ++j) {
      int e = (eb + j) * 16 + l15;
#pragma unroll
      for (int r = 0; r < 4; ++r) {
        int d = dt * 16 + lg * 4 + r;
        op[d * 64 + e] = (__bf16)cacc[j][r];
      }
    }
  }
}

// ---------- GEMM2 fused with bias + out-RMSNorm. BM=64 x BN=512 x BK=64.
// LDS-staged, counted-vmcnt 2-deep schedule (proven R13 version).
__global__ __launch_bounds__(512) void gemm2rms(const __bf16* __restrict__ QS,
                                                const __bf16* __restrict__ W2T,
                                                const float* __restrict__ bias,
                                                const float* __restrict__ onw,
                                                float* __restrict__ out) {
  __shared__ __bf16 As[2][64 * 64];
  __shared__ __bf16 Bs[2][512 * 64];
  __shared__ float rss[64][8];
  const int K = 512;
  const int NT = 8;
  const int tid = threadIdx.x;
  const int lane = tid & 63;
  const int wave = tid >> 6;
  const int wc = wave * 64;
  const int l15 = lane & 15, lg = lane >> 4;
  const int cpx = gridDim.x >> 3;
  const int fid = blockIdx.x;
  const int tile = (fid & 7) * cpx + (fid >> 3);
  const int m0 = tile * 64;
  const __bf16* bt = W2T + (size_t)(m0 >> 12) * 262144;

  f32x4 acc[4][4] = {};

  auto stage = [&](int buf, int k0) {
    {
      int flat = tid;
      int row = flat >> 3;
      int cb = ((flat & 7) ^ (row & 7)) * 16;
      gload_lds16((const char*)(QS + (size_t)(m0 + row) * K + k0) + cb,
                  (char*)(&As[buf][0]) + flat * 16);
    }
#pragma unroll
    for (int it = 0; it < 8; ++it) {
      int flat = it * 512 + tid;
      int row = flat >> 3;
      int cb = ((flat & 7) ^ (row & 7)) * 16;
      gload_lds16((const char*)(bt + (size_t)row * K + k0) + cb,
                  (char*)(&Bs[buf][0]) + flat * 16);
    }
  };

  stage(0, 0);
  stage(1, 64);
  asm volatile("s_waitcnt vmcnt(9)" ::: "memory");
  __builtin_amdgcn_s_barrier();

  for (int kt = 0; kt < NT; ++kt) {
    const int cur = kt & 1;
    bf16x8 a0[4], b0[4], a1[4], b1[4];
    const int sw0 = lg ^ (l15 & 7);
    const int sw1 = (4 + lg) ^ (l15 & 7);
#pragma unroll
    for (int i = 0; i < 4; ++i) {
      a0[i] = *(const bf16x8*)(&As[cur][(i * 16 + l15) * 64 + sw0 * 8]);
      b0[i] = *(const bf16x8*)(&Bs[cur][(wc + i * 16 + l15) * 64 + sw0 * 8]);
      a1[i] = *(const bf16x8*)(&As[cur][(i * 16 + l15) * 64 + sw1 * 8]);
      b1[i] = *(const bf16x8*)(&Bs[cur][(wc + i * 16 + l15) * 64 + sw1 * 8]);
    }
    asm volatile("s_waitcnt lgkmcnt(0)" ::: "memory");
    __builtin_amdgcn_sched_barrier(0);
    __builtin_amdgcn_s_barrier();  // buf[cur] consumed
    if (kt + 2 < NT) stage(cur, (kt + 2) * 64);
    __builtin_amdgcn_s_setprio(1);
#pragma unroll
    for (int mi = 0; mi < 4; ++mi)
#pragma unroll
      for (int ni = 0; ni < 4; ++ni)
        acc[mi][ni] = __builtin_amdgcn_mfma_f32_16x16x32_bf16(a0[mi], b0[ni],
                                                              acc[mi][ni], 0, 0, 0);
    __builtin_amdgcn_s_setprio(0);
    __builtin_amdgcn_s_setprio(1);
#pragma unroll
    for (int mi = 0; mi < 4; ++mi)
#pragma unroll
      for (int ni = 0; ni < 4; ++ni)
        acc[mi][ni] = __builtin_amdgcn_mfma_f32_16x16x32_bf16(a1[mi], b1[ni],
                                                              acc[mi][ni], 0, 0, 0);
    __builtin_amdgcn_s_setprio(0);
    if (kt < NT - 1) {
      if (kt + 2 < NT)
        asm volatile("s_waitcnt vmcnt(9)" ::: "memory");
      else
        asm volatile("s_waitcnt vmcnt(0)" ::: "memory");
      __builtin_amdgcn_s_barrier();
    }
  }

  float bv[4], wv[4];
#pragma unroll
  for (int ni = 0; ni < 4; ++ni) {
    int col = wc + ni * 16 + l15;
    bv[ni] = bias[col];
    wv[ni] = onw[col];
  }
  float vv[4][4][4];
#pragma unroll
  for (int mi = 0; mi < 4; ++mi)
#pragma unroll
    for (int ni = 0; ni < 4; ++ni)
#pragma unroll
      for (int r = 0; r < 4; ++r) vv[mi][ni][r] = acc[mi][ni][r] + bv[ni];
#pragma unroll
  for (int mi = 0; mi < 4; ++mi)
#pragma unroll
    for (int r = 0; r < 4; ++r) {
      float ps = vv[mi][0][r] * vv[mi][0][r] + vv[mi][1][r] * vv[mi][1][r] +
                 vv[mi][2][r] * vv[mi][2][r] + vv[mi][3][r] * vv[mi][3][r];
#pragma unroll
      for (int m = 1; m < 16; m <<= 1) ps += __shfl_xor(ps, m);
      if (l15 == 0) rss[mi * 16 + lg * 4 + r][wave] = ps;
    }
  __syncthreads();
#pragma unroll
  for (int mi = 0; mi < 4; ++mi)
#pragma unroll
    for (int r = 0; r < 4; ++r) {
      int row = mi * 16 + lg * 4 + r;
      float ss = rss[row][0] + rss[row][1] + rss[row][2] + rss[row][3] +
                 rss[row][4] + rss[row][5] + rss[row][6] + rss[row][7];
      float sc = SQRT_DIM / fmaxf(sqrtf(ss), 1e-12f);
      size_t rb = (size_t)(m0 + row) * 512;
#pragma unroll
      for (int ni = 0; ni < 4; ++ni)
        out[rb + wc + ni * 16 + l15] = vv[mi][ni][r] * sc * wv[ni];
    }
}

// ---------- ctx_final: 256 blocks = bh(32) x dgroup(8). Each block: 8 d-rows.
__global__ __launch_bounds__(256) void ctx_final(const __bf16* __restrict__ pctx,
                                                 const float* __restrict__ pden,
                                                 const float* __restrict__ memkv,
                                                 float* __restrict__ ctx) {
  const int bh = blockIdx.x >> 3, dg = blockIdx.x & 7;
  const int h = bh & 7;
  const int tid = threadIdx.x;
  __shared__ float sden[8][9];
  if (tid < 64) {
    const int dl = tid >> 3, part = tid & 7;
    const int d = dg * 8 + dl;
    float s = 0.0f;
#pragma unroll
    for (int c = 0; c < 4; ++c)
      s += pden[((size_t)bh * 32 + part * 4 + c) * 64 + d];
    if (part == 0) {
#pragma unroll
      for (int m = 0; m < 8; ++m)
        s += __expf(memkv[(size_t)h * 512 + d * 8 + m]);
    }
    sden[dl][part] = s;
  }
  __syncthreads();
  const int dl = tid >> 5, e2 = (tid & 31) * 2;
  const int d = dg * 8 + dl;
  float den = sden[dl][0] + sden[dl][1] + sden[dl][2] + sden[dl][3] +
              sden[dl][4] + sden[dl][5] + sden[dl][6] + sden[dl][7];
  float invd = 1.0f / den;
  float s0 = 0.0f, s1 = 0.0f;
#pragma unroll
  for (int m = 0; m < 8; ++m) {
    float ek = __expf(memkv[(size_t)h * 512 + d * 8 + m]);
    s0 += ek * memkv[4096 + (size_t)h * 512 + e2 * 8 + m];
    s1 += ek * memkv[4096 + (size_t)h * 512 + (e2 + 1) * 8 + m];
  }
#pragma unroll
  for (int c = 0; c < 32; ++c) {
    bf16x2 p = *(const bf16x2*)(pctx + ((size_t)bh * 32 + c) * 4096 + d * 64 + e2);
    s0 += (float)p[0];
    s1 += (float)p[1];
  }
  float2 o = make_float2(s0 * invd, s1 * invd);
  *(float2*)(ctx + (size_t)bh * 4096 + d * 64 + e2) = o;
}

// ---------- make_w2t: 256 blocks = b(4) x h(8) x jc(8), j0 = jc*64.
__global__ __launch_bounds__(256) void make_w2t(const float* __restrict__ ctx,
                                                const float* __restrict__ wout,
                                                __bf16* __restrict__ W2T) {
  const int wg = blockIdx.x;
  const int b = wg >> 6, h = (wg >> 3) & 7, jc = wg & 7;
  const int j0 = jc * 64;
  const int tid = threadIdx.x;
  __shared__ float cs[64][65];
  __shared__ float wo[64][64];
  const float* ch = ctx + ((size_t)b * 8 + h) * 4096;
#pragma unroll
  for (int it = 0; it < 16; ++it) {
    int flat = it * 256 + tid;
    cs[flat >> 6][flat & 63] = ch[flat];
  }
#pragma unroll
  for (int it = 0; it < 16; ++it) {
    int flat = it * 256 + tid;
    int e = flat >> 6, j = flat & 63;
    wo[e][j] = wout[(size_t)(h * 64 + e) * 512 + j0 + j];
  }
  __syncthreads();
  const int d = tid & 63;
  const int jg = (tid >> 6) * 16;
  for (int jj = 0; jj < 16; ++jj) {
    int j = jg + jj;
    float s = 0.0f;
#pragma unroll
    for (int e = 0; e < 64; ++e) s += cs[d][e] * wo[e][j];
    W2T[(size_t)b * 262144 + (size_t)(j0 + j) * 512 + h * 64 + d] = (__bf16)s;
  }
}

extern "C" void kernel_launch(void* const* d_in, const int* in_sizes, int n_in,
                              void* d_out, int out_size, void* d_ws, size_t ws_size,
                              hipStream_t stream) {
  const float* x = (const float*)d_in[0];
  const float* norm_w = (const float*)d_in[1];
  const float* w_qkv = (const float*)d_in[2];
  const float* mem_kv = (const float*)d_in[3];
  const float* w_out = (const float*)d_in[4];
  const float* b_out = (const float*)d_in[5];
  const float* onw = (const float*)d_in[6];

  char* ws = (char*)d_ws;
  __bf16* xn = (__bf16*)(ws + 0);            // 16 MB
  __bf16* WqkvT = (__bf16*)(ws + 16777216);  // 1.5 MB
  __bf16* pctx = (__bf16*)(ws + 18350080);   // 8 MB (bf16)
  __bf16* QS = (__bf16*)(ws + 51904512);     // 16 MB
  float* pden = (float*)(ws + 68681728);     // 256 KB
  float* ctx = (float*)(ws + 68943872);      // 512 KB
  __bf16* W2T = (__bf16*)(ws + 69468160);    // 2 MB

  pre_k<<<4288, 256, 0, stream>>>(x, norm_w, xn, w_qkv, WqkvT);
  gemm1_k<<<1536, 512, 0, stream>>>(xn, WqkvT, QS, pctx, pden);
  ctx_final<<<256, 256, 0, stream>>>(pctx, pden, mem_kv, ctx);
  make_w2t<<<256, 256, 0, stream>>>(ctx, w_out, W2T);
  gemm2rms<<<256, 512, 0, stream>>>(QS, W2T, b_out, onw, (float*)d_out);
}